// Round 15
// baseline (250.753 us; speedup 1.0000x reference)
//
#include <hip/hip_runtime.h>
#include <stdint.h>

typedef int   int32x4   __attribute__((ext_vector_type(4)));
typedef int   int32x16  __attribute__((ext_vector_type(16)));
typedef float floatx4   __attribute__((ext_vector_type(4)));

#define B_ROWS 131072
#define DK 512           // K (= D)
#define FN 512           // N (= F)
#define A_SCALE_F ((float)(127.0 / 6.0))

// fused-GEMM geometry: 512 blocks x 512 threads (8 waves), TWO blocks/CU.
// No B-in-registers: B fragments stream from L2 inside the K-loop, cutting
// per-wave regs from 256 to ~125 -> 4 waves/SIMD -> two co-resident blocks
// whose barrier stalls mutually overlap. Wave w owns cols [w*64, w*64+64).
#define GBLK 512
#define GT   512
#define BMS  32
#define GTILES (B_ROWS / BMS / GBLK)   // 8

// ---------------- prepass: quantize weights into B-fragment layout -------------
__global__ void wq_quant_kernel(const float* __restrict__ kern,  // [DK][FN]
                                int8_t* __restrict__ wq,         // [FN][DK]
                                float* __restrict__ invcs) {     // [FN]
  __shared__ float smax[256];
  __shared__ float sscale[4];
  const int c = threadIdx.x & 3;         // col within block
  const int g = threadIdx.x >> 2;        // row-group 0..63 (8 rows each)
  const int col = blockIdx.x * 4 + c;

  float m = 0.f;
#pragma unroll
  for (int i = 0; i < 8; ++i) {
    m = fmaxf(m, fabsf(kern[(size_t)(g * 8 + i) * FN + col]));
  }
  smax[threadIdx.x] = m;
  __syncthreads();
  if (threadIdx.x < 4) {
    float mm = smax[threadIdx.x];
#pragma unroll 8
    for (int g2 = 1; g2 < 64; ++g2) mm = fmaxf(mm, smax[g2 * 4 + threadIdx.x]);
    const float wb = fmaxf(mm, 1e-6f);
    const float ws = 127.f / wb;               // f32 divide, matches jnp w_scale
    sscale[threadIdx.x] = ws;
    invcs[blockIdx.x * 4 + threadIdx.x] =
        (float)(1.0 / ((double)A_SCALE_F * (double)ws));
  }
  __syncthreads();
  const float ws = sscale[c];
  uint32_t* wq32 = (uint32_t*)(wq + (size_t)col * DK);
#pragma unroll
  for (int d = 0; d < 2; ++d) {                // 8 rows -> 2 packed words
    uint32_t p = 0;
#pragma unroll
    for (int j = 0; j < 4; ++j) {
      float v = kern[(size_t)(g * 8 + d * 4 + j) * FN + col] * ws;
      v = floorf(v + 0.5f);                    // AQT round: floor(v+0.5)
      v = fminf(fmaxf(v, -127.f), 127.f);
      p |= ((uint32_t)((int)v & 255)) << (8 * j);
    }
    wq32[g * 2 + d] = p;
  }
}

// ---------------- fused GEMM: B streamed from L2, 2 blocks/CU ------------------
__device__ __forceinline__ uint32_t quant4(floatx4 v) {
  uint32_t p = 0;
#pragma unroll
  for (int j = 0; j < 4; ++j) {
    float q = floorf(v[j] * A_SCALE_F + 0.5f);   // AQT round: floor(v+0.5)
    q = fminf(fmaxf(q, -127.f), 127.f);
    p |= ((uint32_t)((int)q & 255)) << (8 * j);
  }
  return p;
}

__global__ __launch_bounds__(GT, 4)
void aqt_gemm_fused(const float* __restrict__ x,     // [B_ROWS][DK]
                    const int8_t* __restrict__ wq,   // [FN][DK]
                    const float* __restrict__ invcs, // [FN]
                    const float* __restrict__ bias,  // [FN]
                    float* __restrict__ out) {       // [B_ROWS][FN]
  __shared__ __align__(16) uint8_t xq[2][BMS * DK];  // 2 x 16 KB

  const int tid  = threadIdx.x;
  const int lane = tid & 63;
  const int wv   = tid >> 6;       // 0..7 -> col strip w*64
  const int l31  = lane & 31;
  const int l5   = lane >> 5;

  const int c4 = tid & 127;        // float4 col within a row
  const int rg = tid >> 7;         // 0..3 -> rows rg, rg+4, ..., rg+28

  // per-wave B base pointers (L2-resident; K-step folds into imm offsets)
  const int col0 = wv * 64 + l31;
  const int col1 = col0 + 32;
  const int8_t* bp0 = wq + (size_t)col0 * DK + l5 * 16;
  const int8_t* bp1 = bp0 + (size_t)32 * DK;
  const float inv0 = invcs[col0], bv0 = bias[col0];
  const float inv1 = invcs[col1], bv1 = bias[col1];

  const size_t row0 = (size_t)blockIdx.x * (GTILES * BMS);

  // issue the 8 f32 tile loads for tile starting at row rt
#define LOADV(vdst, rt)                                                       \
  {                                                                           \
    const float* xg_ = x + (size_t)(rt) * DK;                                 \
    _Pragma("unroll")                                                         \
    for (int i_ = 0; i_ < 8; ++i_)                                            \
      vdst[i_] = *(const floatx4*)(xg_ + (size_t)(i_ * 4 + rg) * DK + c4 * 4);\
  }

  // quantize 8 granules into LDS buffer (XOR-swizzled)
#define QWRITE(vsrc, bufp)                                                    \
  {                                                                           \
    _Pragma("unroll")                                                         \
    for (int i_ = 0; i_ < 8; ++i_) {                                          \
      const int r_ = i_ * 4 + rg;                                             \
      *(uint32_t*)(&(bufp)[r_ * DK + ((c4 * 4) ^ ((r_ & 31) << 4))]) =        \
          quant4(vsrc[i_]);                                                   \
    }                                                                         \
  }

  floatx4 vA[8];

  // ---- prologue: tile 0 staged (startup stall, once) ----
  LOADV(vA, row0);
  QWRITE(vA, (&xq[0][0]));
  asm volatile("s_waitcnt lgkmcnt(0)" ::: "memory");
  __builtin_amdgcn_s_barrier();

#pragma unroll 1
  for (int t = 0; t < GTILES; ++t) {
    const size_t rowT = row0 + (size_t)t * BMS;
    const uint8_t* bufC = &xq[t & 1][0];
    uint8_t* bufN = &xq[(t & 1) ^ 1][0];
    const bool pf = (t + 1 < GTILES);

    // x loads for t+1 (oldest in vmem queue; overlap the whole K-loop)
    if (pf) LOADV(vA, rowT + BMS);

    // K-loop: A from LDS (read once), B streamed from L2, both panels fused
    int32x16 acc0 = (int32x16)(0);
    int32x16 acc1 = (int32x16)(0);
    {
      const uint8_t* aRow = bufC + l31 * DK;
      const int aswz = l31 << 4;
#pragma unroll
      for (int ks = 0; ks < 16; ++ks) {
        int32x4 a  = *(const int32x4*)(aRow + ((ks * 32 + l5 * 16) ^ aswz));
        int32x4 b0 = *(const int32x4*)(bp0 + ks * 32);
        int32x4 b1 = *(const int32x4*)(bp1 + ks * 32);
        acc0 = __builtin_amdgcn_mfma_i32_32x32x32_i8(a, b0, acc0, 0, 0, 0);
        acc1 = __builtin_amdgcn_mfma_i32_32x32x32_i8(a, b1, acc1, 0, 0, 0);
      }
    }

    // quantize t+1 (its loads are the only outstanding vmem reads by now)
    if (pf) QWRITE(vA, bufN);

    // epilogue: both panels, full-128B-segment NT stores
#pragma unroll
    for (int r = 0; r < 16; ++r) {
      const int rowl = (r & 3) + 8 * (r >> 2) + 4 * l5;
      __builtin_nontemporal_store((float)acc0[r] * inv0 + bv0,
                                  &out[(rowT + rowl) * FN + col0]);
    }
#pragma unroll
    for (int r = 0; r < 16; ++r) {
      const int rowl = (r & 3) + 8 * (r >> 2) + 4 * l5;
      __builtin_nontemporal_store((float)acc1[r] * inv1 + bv1,
                                  &out[(rowT + rowl) * FN + col1]);
    }

    asm volatile("s_waitcnt lgkmcnt(0)" ::: "memory");
    __builtin_amdgcn_s_barrier();
  }

#undef LOADV
#undef QWRITE
}

extern "C" void kernel_launch(void* const* d_in, const int* in_sizes, int n_in,
                              void* d_out, int out_size, void* d_ws, size_t ws_size,
                              hipStream_t stream) {
  const float* x    = (const float*)d_in[0];
  const float* kern = (const float*)d_in[1];
  const float* bias = (const float*)d_in[2];
  // d_in[3] = padding_mask: fixed act bounds + eval mode -> not in the math.

  int8_t* wq    = (int8_t*)d_ws;                            // 256 KB
  float*  invcs = (float*)((char*)d_ws + (size_t)FN * DK);  // 2 KB

  wq_quant_kernel<<<128, 256, 0, stream>>>(kern, wq, invcs);
  aqt_gemm_fused<<<GBLK, GT, 0, stream>>>(x, wq, invcs, bias, (float*)d_out);
}

// Round 16
// 111.572 us; speedup vs baseline: 2.2475x; 2.2475x over previous
//
#include <hip/hip_runtime.h>
#include <stdint.h>

typedef int   int32x4   __attribute__((ext_vector_type(4)));
typedef int   int32x16  __attribute__((ext_vector_type(16)));
typedef float floatx4   __attribute__((ext_vector_type(4)));

#define B_ROWS 131072
#define DK 512           // K (= D)
#define FN 512           // N (= F)
#define A_SCALE_F ((float)(127.0 / 6.0))

// fused-GEMM geometry: 512 blocks x 512 threads (8 waves). Per-wave 256 regs
// (Bf0+Bf1 = 128 AGPR + ~128 VGPR) -> 8 waves/CU. R13 structure (best: 110.9us)
// with one delta: v_perm-based quant4 (fewer serialized VALU ops per tile).
#define GBLK 512
#define GT   512
#define BMS  32
#define GTILES (B_ROWS / BMS / GBLK)   // 8 (even, required by the 2-unroll)

// ---------------- prepass: quantize weights into B-fragment layout -------------
__global__ void wq_quant_kernel(const float* __restrict__ kern,  // [DK][FN]
                                int8_t* __restrict__ wq,         // [FN][DK]
                                float* __restrict__ invcs) {     // [FN]
  __shared__ float smax[256];
  __shared__ float sscale[4];
  const int c = threadIdx.x & 3;         // col within block
  const int g = threadIdx.x >> 2;        // row-group 0..63 (8 rows each)
  const int col = blockIdx.x * 4 + c;

  float m = 0.f;
#pragma unroll
  for (int i = 0; i < 8; ++i) {
    m = fmaxf(m, fabsf(kern[(size_t)(g * 8 + i) * FN + col]));
  }
  smax[threadIdx.x] = m;
  __syncthreads();
  if (threadIdx.x < 4) {
    float mm = smax[threadIdx.x];
#pragma unroll 8
    for (int g2 = 1; g2 < 64; ++g2) mm = fmaxf(mm, smax[g2 * 4 + threadIdx.x]);
    const float wb = fmaxf(mm, 1e-6f);
    const float ws = 127.f / wb;               // f32 divide, matches jnp w_scale
    sscale[threadIdx.x] = ws;
    invcs[blockIdx.x * 4 + threadIdx.x] =
        (float)(1.0 / ((double)A_SCALE_F * (double)ws));
  }
  __syncthreads();
  const float ws = sscale[c];
  uint32_t* wq32 = (uint32_t*)(wq + (size_t)col * DK);
#pragma unroll
  for (int d = 0; d < 2; ++d) {                // 8 rows -> 2 packed words
    uint32_t p = 0;
#pragma unroll
    for (int j = 0; j < 4; ++j) {
      float v = kern[(size_t)(g * 8 + d * 4 + j) * FN + col] * ws;
      v = floorf(v + 0.5f);                    // AQT round: floor(v+0.5)
      v = fminf(fmaxf(v, -127.f), 127.f);
      p |= ((uint32_t)((int)v & 255)) << (8 * j);
    }
    wq32[g * 2 + d] = p;
  }
}

// ---------------- fast quantize: fma/floor/clamp/cvt + v_perm byte pack --------
// ~23 VALU ops per granule vs ~32 for the shift/or version; this VALU sits on
// the serialized critical path between K-loop and barrier (no co-resident
// block can cover it), so fewer ops -> directly shorter tile period.
__device__ __forceinline__ uint32_t quant4(floatx4 v) {
  int32x4 q;
#pragma unroll
  for (int j = 0; j < 4; ++j) {
    float f = floorf(fmaf(v[j], A_SCALE_F, 0.5f));   // AQT round: floor(v+0.5)
    f = fminf(fmaxf(f, -127.f), 127.f);
    q[j] = (int)f;
  }
  uint32_t w01 = __builtin_amdgcn_perm((uint32_t)q[1], (uint32_t)q[0], 0x00000400u);
  uint32_t w23 = __builtin_amdgcn_perm((uint32_t)q[3], (uint32_t)q[2], 0x00000400u);
  return __builtin_amdgcn_perm(w23, w01, 0x05040100u);  // bytes [q0,q1,q2,q3]
}

__global__ __launch_bounds__(GT, 2)
void aqt_gemm_fused(const float* __restrict__ x,     // [B_ROWS][DK]
                    const int8_t* __restrict__ wq,   // [FN][DK]
                    const float* __restrict__ invcs, // [FN]
                    const float* __restrict__ bias,  // [FN]
                    float* __restrict__ out) {       // [B_ROWS][FN]
  __shared__ __align__(16) uint8_t xq[2][BMS * DK];  // 2 x 16 KB

  const int tid  = threadIdx.x;
  const int lane = tid & 63;
  const int wv   = tid >> 6;       // 0..7 -> col strip w*64
  const int l31  = lane & 31;
  const int l5   = lane >> 5;

  const int c4 = tid & 127;        // float4 col within a row
  const int rg = tid >> 7;         // 0..3 -> rows rg, rg+4, ..., rg+28

  // ---- B fragments into registers, once (256 KB, L2-hot): 2 panels ----
  const int col0 = wv * 64 + l31;
  const int col1 = col0 + 32;
  int32x4 Bf0[16], Bf1[16];
#pragma unroll
  for (int ks = 0; ks < 16; ++ks) {
    Bf0[ks] = *(const int32x4*)(wq + (size_t)col0 * DK + ks * 32 + l5 * 16);
    Bf1[ks] = *(const int32x4*)(wq + (size_t)col1 * DK + ks * 32 + l5 * 16);
  }
  const float inv0 = invcs[col0], bv0 = bias[col0];
  const float inv1 = invcs[col1], bv1 = bias[col1];

  const size_t row0 = (size_t)blockIdx.x * (GTILES * BMS);

  // issue the 8 f32 tile loads for tile starting at row rt
#define LOADV(vdst, rt)                                                       \
  {                                                                           \
    const float* xg_ = x + (size_t)(rt) * DK;                                 \
    _Pragma("unroll")                                                         \
    for (int i_ = 0; i_ < 8; ++i_)                                            \
      vdst[i_] = *(const floatx4*)(xg_ + (size_t)(i_ * 4 + rg) * DK + c4 * 4);\
  }

  // quantize 8 granules into LDS buffer (XOR-swizzled)
#define QWRITE(vsrc, bufp)                                                    \
  {                                                                           \
    _Pragma("unroll")                                                         \
    for (int i_ = 0; i_ < 8; ++i_) {                                          \
      const int r_ = i_ * 4 + rg;                                             \
      *(uint32_t*)(&(bufp)[r_ * DK + ((c4 * 4) ^ ((r_ & 31) << 4))]) =        \
          quant4(vsrc[i_]);                                                   \
    }                                                                         \
  }

  // one 32-col panel: K-loop + epilogue NT stores (acc lives only inside)
#define PANEL(Bf, colv, invv, bvv, bufp, rt)                                  \
  {                                                                           \
    int32x16 acc = (int32x16)(0);                                             \
    const uint8_t* aRow_ = (bufp) + l31 * DK;                                 \
    _Pragma("unroll")                                                         \
    for (int ks_ = 0; ks_ < 16; ++ks_) {                                      \
      int32x4 a_ = *(const int32x4*)(aRow_ + ((ks_ * 32 + l5 * 16) ^ (l31 << 4))); \
      acc = __builtin_amdgcn_mfma_i32_32x32x32_i8(a_, Bf[ks_], acc, 0, 0, 0); \
    }                                                                         \
    _Pragma("unroll")                                                         \
    for (int r_ = 0; r_ < 16; ++r_) {                                         \
      const int rowl_ = (r_ & 3) + 8 * (r_ >> 2) + 4 * l5;                    \
      __builtin_nontemporal_store((float)acc[r_] * (invv) + (bvv),            \
                                  &out[((rt) + rowl_) * FN + (colv)]);        \
    }                                                                         \
  }

  floatx4 vA[8], vB[8];

  // ---- prologue: tile 0 staged (startup stall, once); tile 1 in flight ----
  LOADV(vA, row0);
  QWRITE(vA, (&xq[0][0]));
  LOADV(vB, row0 + BMS);
  asm volatile("s_waitcnt lgkmcnt(0)" ::: "memory");
  __builtin_amdgcn_s_barrier();

#pragma unroll 1
  for (int t = 0; t < GTILES; t += 2) {
    const size_t rowT = row0 + (size_t)t * BMS;

    // even: compute buf0 (tile t); prefetch vA <- t+2; quantize vB -> buf1
    if (t + 2 < GTILES) LOADV(vA, rowT + 2 * BMS);
    PANEL(Bf0, col0, inv0, bv0, (&xq[0][0]), rowT);
    PANEL(Bf1, col1, inv1, bv1, (&xq[0][0]), rowT);
    QWRITE(vB, (&xq[1][0]));              // tile t+1 (always < GTILES)
    asm volatile("s_waitcnt lgkmcnt(0)" ::: "memory");
    __builtin_amdgcn_s_barrier();

    // odd: compute buf1 (tile t+1); prefetch vB <- t+3; quantize vA -> buf0
    if (t + 3 < GTILES) LOADV(vB, rowT + 3 * BMS);
    PANEL(Bf0, col0, inv0, bv0, (&xq[1][0]), rowT + BMS);
    PANEL(Bf1, col1, inv1, bv1, (&xq[1][0]), rowT + BMS);
    if (t + 2 < GTILES) QWRITE(vA, (&xq[0][0]));
    asm volatile("s_waitcnt lgkmcnt(0)" ::: "memory");
    __builtin_amdgcn_s_barrier();
  }

#undef LOADV
#undef QWRITE
#undef PANEL
}

extern "C" void kernel_launch(void* const* d_in, const int* in_sizes, int n_in,
                              void* d_out, int out_size, void* d_ws, size_t ws_size,
                              hipStream_t stream) {
  const float* x    = (const float*)d_in[0];
  const float* kern = (const float*)d_in[1];
  const float* bias = (const float*)d_in[2];
  // d_in[3] = padding_mask: fixed act bounds + eval mode -> not in the math.

  int8_t* wq    = (int8_t*)d_ws;                            // 256 KB
  float*  invcs = (float*)((char*)d_ws + (size_t)FN * DK);  // 2 KB

  wq_quant_kernel<<<128, 256, 0, stream>>>(kern, wq, invcs);
  aqt_gemm_fused<<<GBLK, GT, 0, stream>>>(x, wq, invcs, bias, (float*)d_out);
}